// Round 6
// baseline (810.622 us; speedup 1.0000x reference)
//
#include <hip/hip_runtime.h>

// GCN layer on MI355X — round 6.
//   prep_zero:      Wsw (bf16 MFMA-B swizzle, column-permuted so lane m's 8
//                   accumulators are natural cols m*8..m*8+7), natural BN
//                   scale/shift + bias, cur=0
//   degree_count:   histogram of dst
//   linear_mfma:    h = bf16(x@W+b), NATURAL channel order, coalesced 16B
//                   stores (permutation folded into Wsw swizzle — free)
//   scan1/scan3m:   exclusive scan -> off (+cursor copy)
//   csr_fill_part:  XCD-partitioned fill (r4 win)
//   gather_bn_relu: XCD CHANNEL-SPLIT: group p=blockIdx&7 reads only 32B of
//                   each h row -> per-XCD working set 6.4MB; 2-phase src-range
//                   blocking halves it to 3.2MB -> fits 4MiB L2. (r5: each XCD
//                   read all of h, 15% L2 hit, FETCH=179MB, LLC-bound 88us.)
// mean(h[src]) = mean(x[src])@W + b (linearity); deg=0 -> sum=0 -> relu(sh).

#define NN 100000
#define NE 1600000
#define CC 128
#define BN_EPS 1e-5f
#define NB 391        // ceil(NN/256)
#define LBLK 1563     // ceil(NN/64) linear blocks
#define FCHUNKS 256   // csr_fill chunks per partition
#define FCHUNK 6250   // 256*6250 = NE
#define PARTN 12500   // NN/8 dst nodes per XCD partition
#define LSTR 136      // LDS row stride in bf16 (128 + 8 pad)
#define GCH 6250      // gather dst chunks (16 nodes each)

typedef __attribute__((ext_vector_type(8))) short bf16x8;
typedef __attribute__((ext_vector_type(4))) float f32x4;

static __device__ __forceinline__ short f2bf(float f) {
  union { float f; unsigned u; } v; v.f = f;
  unsigned r = (v.u + 0x7FFF + ((v.u >> 16) & 1)) >> 16;  // RNE
  return (short)r;
}
static __device__ __forceinline__ float bflo(unsigned p) {
  return __uint_as_float(p << 16);
}
static __device__ __forceinline__ float bfhi(unsigned p) {
  return __uint_as_float(p & 0xffff0000u);
}

// ---------------------------------------------------------------------------
// prep_zero: zero cursor; swizzle W into bf16 B-fragments with the COLUMN
// PERMUTATION col(nt,m) = m*8+nt (so D-lane m holds 8 consecutive natural
// cols); natural-order BN scale/shift and bias.
// B-frag (16x16x32): lane = mslot + 16*quad holds B[kb*32+quad*8+j][col].
// ---------------------------------------------------------------------------
__global__ __launch_bounds__(256) void prep_zero(
    const float* __restrict__ W, const float* __restrict__ bias,
    const float* __restrict__ gamma, const float* __restrict__ beta,
    const float* __restrict__ rmean, const float* __restrict__ rvar,
    short* __restrict__ Wsw, float* __restrict__ scsh,
    int* __restrict__ cur) {
  const int i = blockIdx.x * 256 + threadIdx.x;
  if (i < NN) cur[i] = 0;
  if (i < CC * CC) {
    const int k = i >> 7, n = i & 127;
    const int nt = n & 7, m = n >> 3;           // col n lives in tile nt, slot m
    const int kb = k >> 5, q = (k >> 3) & 3, j = k & 7;
    Wsw[(size_t)(((nt * 4 + kb) * 64 + (m + 16 * q)) * 8 + j)] = f2bf(W[i]);
  }
  if (i < CC) {
    const float sc = gamma[i] * rsqrtf(rvar[i] + BN_EPS);
    scsh[i] = sc;
    scsh[CC + i] = beta[i] - rmean[i] * sc;
    scsh[2 * CC + i] = bias[i];
  }
}

// ---------------------------------------------------------------------------
// degree_count: 1.6M int atomics.
// ---------------------------------------------------------------------------
__global__ __launch_bounds__(256) void degree_count(const int* __restrict__ ei,
                                                    int* __restrict__ cnt) {
  int e = blockIdx.x * 256 + threadIdx.x;
  if (e >= NE) return;
  atomicAdd(cnt + ei[NE + e], 1);
}

// ---------------------------------------------------------------------------
// linear_mfma: h = bf16(x@W+b), 64 rows/block, 4 waves x 16 rows.
// LDS-staged coalesced loads; MFMA with permuted-column Wsw; lane m's 8
// accumulators = natural cols m*8..+7 -> one bf16x8 coalesced store per row.
// ---------------------------------------------------------------------------
__global__ __launch_bounds__(256) void linear_mfma(
    const float* __restrict__ x, const short* __restrict__ Wsw,
    const float* __restrict__ scsh, short* __restrict__ hout) {
  __shared__ short lsA[64 * LSTR];  // 17.4 KB
  const int t = threadIdx.x;
  const int n0 = blockIdx.x * 64;

#pragma unroll
  for (int j = 0; j < 8; ++j) {
    const int idx = j * 256 + t;
    const int row = idx >> 5, kc4 = idx & 31;
    float4 v = make_float4(0.f, 0.f, 0.f, 0.f);
    if (n0 + row < NN) v = *(const float4*)(x + (size_t)(n0 + row) * CC + kc4 * 4);
    short4 s;
    s.x = f2bf(v.x); s.y = f2bf(v.y); s.z = f2bf(v.z); s.w = f2bf(v.w);
    *(short4*)(lsA + row * LSTR + kc4 * 4) = s;
  }
  __syncthreads();

  const int wave = t >> 6, lane = t & 63;
  const int quad = lane >> 4, m = lane & 15;
  const int rowbase = n0 + wave * 16;

  f32x4 acc[8];
#pragma unroll
  for (int nt = 0; nt < 8; ++nt) acc[nt] = (f32x4){0.f, 0.f, 0.f, 0.f};

#pragma unroll
  for (int kb = 0; kb < 4; ++kb) {
    const bf16x8 a =
        *(const bf16x8*)(lsA + (wave * 16 + m) * LSTR + kb * 32 + quad * 8);
#pragma unroll
    for (int nt = 0; nt < 8; ++nt) {
      bf16x8 b = *(const bf16x8*)(Wsw + (size_t)(((nt * 4 + kb) * 64 + lane) * 8));
      acc[nt] = __builtin_amdgcn_mfma_f32_16x16x32_bf16(a, b, acc[nt], 0, 0, 0);
    }
  }

  // natural bias, contiguous at m*8 (acc[nt] is natural col m*8+nt).
  const float4 b0 = *(const float4*)(scsh + 2 * CC + m * 8);
  const float4 b1 = *(const float4*)(scsh + 2 * CC + m * 8 + 4);
  const float bv[8] = {b0.x, b0.y, b0.z, b0.w, b1.x, b1.y, b1.z, b1.w};

#pragma unroll
  for (int reg = 0; reg < 4; ++reg) {
    const int R = rowbase + quad * 4 + reg;
    if (R >= NN) continue;
    bf16x8 hv;
#pragma unroll
    for (int nt = 0; nt < 8; ++nt) hv[nt] = f2bf(acc[nt][reg] + bv[nt]);
    *(bf16x8*)(hout + (size_t)R * CC + m * 8) = hv;  // natural, 16B coalesced
  }
}

// ---------------------------------------------------------------------------
// scan1 / scan3m: exclusive scan -> off (+cursor copy).
// ---------------------------------------------------------------------------
__global__ __launch_bounds__(256) void scan1(const int* __restrict__ cnt,
                                             int* __restrict__ off,
                                             int* __restrict__ bsum) {
  __shared__ int sh[256];
  const int t = threadIdx.x;
  const int i = blockIdx.x * 256 + t;
  const int v = (i < NN) ? cnt[i] : 0;
  sh[t] = v;
  __syncthreads();
  for (int d = 1; d < 256; d <<= 1) {
    int add = (t >= d) ? sh[t - d] : 0;
    __syncthreads();
    sh[t] += add;
    __syncthreads();
  }
  if (i < NN) off[i] = sh[t] - v;
  if (t == 255) bsum[blockIdx.x] = sh[t];
}

__global__ __launch_bounds__(256) void scan3m(int* __restrict__ off,
                                              const int* __restrict__ bsum,
                                              int* __restrict__ cur) {
  __shared__ int sh[256];
  const int b = blockIdx.x, t = threadIdx.x;
  int s = 0;
  for (int j = t; j < b; j += 256) s += bsum[j];
  sh[t] = s;
  __syncthreads();
  for (int d = 128; d > 0; d >>= 1) {
    if (t < d) sh[t] += sh[t + d];
    __syncthreads();
  }
  const int pref = sh[0];
  const int i = b * 256 + t;
  if (i < NN) {
    int o = off[i] + pref;
    off[i] = o;
    cur[i] = o;
  }
  if (i == 0) off[NN] = NE;
}

// ---------------------------------------------------------------------------
// csr_fill, XCD-partitioned (r4 win).
// ---------------------------------------------------------------------------
__global__ __launch_bounds__(256) void csr_fill_part(
    const int* __restrict__ ei, int* __restrict__ cursor,
    int* __restrict__ csr) {
  const int p = blockIdx.x & 7;
  const int c = blockIdx.x >> 3;
  const int lo = p * PARTN, hi = lo + PARTN;
  const int e0 = c * FCHUNK;
  const int e1 = e0 + FCHUNK;
  for (int e = e0 + threadIdx.x; e < e1; e += 256) {
    int dst = ei[NE + e];
    if (dst >= lo && dst < hi) {
      int pos = atomicAdd(cursor + dst, 1);
      csr[pos] = ei[e];
    }
  }
}

// ---------------------------------------------------------------------------
// gather_bn_relu, XCD channel-split:
//   p = blockIdx&7 -> channel group (cols [p*16,(p+1)*16) = 32B of each row)
//                     AND XCD (round-robin mapping, r4-verified heuristic).
//   Per-XCD h working set = 100k x 64B lines = 6.4MB; 2-phase src blocking
//   (src<50k then >=50k) halves to 3.2MB -> fits 4MiB L2.
//   Wave: 8 lanes/edge x 8 edges in flight; butterfly-reduce over edge slots;
//   lanes 0..7 store one 64B line of out (single-writer, full line).
//   csr via nontemporal loads (streams; don't evict hot h lines).
// ---------------------------------------------------------------------------
__global__ __launch_bounds__(256) void gather_bn_relu(
    const short* __restrict__ h, const int* __restrict__ off,
    const int* __restrict__ csr, const float* __restrict__ scsh,
    float* __restrict__ out) {
  const int p = blockIdx.x & 7;
  const int c = blockIdx.x >> 3;
  const int w = threadIdx.x >> 6;
  const int lane = threadIdx.x & 63;
  const int eg = lane >> 3, j = lane & 7;
  const int cu = p * 8 + j;  // uint col within 64-uint row
  const unsigned* hb = (const unsigned*)h;
  const float2 sc = *(const float2*)(scsh + 2 * cu);
  const float2 sh = *(const float2*)(scsh + CC + 2 * cu);
  const int nbase = c * 16 + w * 4;

  for (int k = 0; k < 4; ++k) {
    const int node = nbase + k;
    if (node >= NN) break;
    const int s = off[node], e = off[node + 1];
    float ax = 0.f, ay = 0.f;
#pragma unroll
    for (int ph = 0; ph < 2; ++ph) {
      const int lo = ph * 50000;
      int i = s + eg;
      for (; i + 8 < e; i += 16) {
        const int s0 = __builtin_nontemporal_load(csr + i);
        const int s1 = __builtin_nontemporal_load(csr + i + 8);
        if ((unsigned)(s0 - lo) < 50000u) {
          unsigned u = hb[(size_t)s0 * 64 + cu];
          ax += bflo(u); ay += bfhi(u);
        }
        if ((unsigned)(s1 - lo) < 50000u) {
          unsigned u = hb[(size_t)s1 * 64 + cu];
          ax += bflo(u); ay += bfhi(u);
        }
      }
      if (i < e) {
        const int s0 = __builtin_nontemporal_load(csr + i);
        if ((unsigned)(s0 - lo) < 50000u) {
          unsigned u = hb[(size_t)s0 * 64 + cu];
          ax += bflo(u); ay += bfhi(u);
        }
      }
    }
    // reduce over the 8 edge slots (lane bits 3..5)
#pragma unroll
    for (int d = 8; d < 64; d <<= 1) {
      ax += __shfl_xor(ax, d);
      ay += __shfl_xor(ay, d);
    }
    if (lane < 8) {
      const float inv = (e > s) ? 1.0f / (float)(e - s) : 0.0f;
      float2 o;
      o.x = fmaxf(0.f, ax * inv * sc.x + sh.x);
      o.y = fmaxf(0.f, ay * inv * sc.y + sh.y);
      *(float2*)(out + (size_t)node * CC + 2 * cu) = o;
    }
  }
}

// ---------------------------------------------------------------------------
// Fallback (small ws): atomic scatter + fp32 vector GEMM.
// ---------------------------------------------------------------------------
__global__ __launch_bounds__(256) void edge_scatter(
    const float* __restrict__ x, const int* __restrict__ ei,
    float* __restrict__ sums, int* __restrict__ cnt) {
  int gt = blockIdx.x * 256 + threadIdx.x;
  int e = gt >> 5;
  int sub = gt & 31;
  if (e >= NE) return;
  int src = ei[e];
  int dst = ei[NE + e];
  const float4 v = *(const float4*)(x + (size_t)src * CC + sub * 4);
  float* o = sums + (size_t)dst * CC + sub * 4;
  unsafeAtomicAdd(o + 0, v.x);
  unsafeAtomicAdd(o + 1, v.y);
  unsafeAtomicAdd(o + 2, v.z);
  unsafeAtomicAdd(o + 3, v.w);
  if (sub == 0) atomicAdd(cnt + dst, 1);
}

__global__ __launch_bounds__(256) void gemm_bn_relu_fb(
    float* buf, const float* __restrict__ W, const float* __restrict__ bias,
    const float* __restrict__ gamma, const float* __restrict__ beta,
    const float* __restrict__ rmean, const float* __restrict__ rvar,
    const int* __restrict__ cnt) {
  __shared__ float xsT[CC][65];
  const int t = threadIdx.x;
  const int n0 = blockIdx.x * 64;
  for (int j = 0; j < 8; ++j) {
    int i = t + 256 * j;
    int row = i >> 5;
    int ko = (i & 31) * 4;
    float4 v = make_float4(0.f, 0.f, 0.f, 0.f);
    if (n0 + row < NN) v = *(const float4*)(buf + (size_t)(n0 + row) * CC + ko);
    xsT[ko + 0][row] = v.x;
    xsT[ko + 1][row] = v.y;
    xsT[ko + 2][row] = v.z;
    xsT[ko + 3][row] = v.w;
  }
  __syncthreads();
  const int cg = t & 31;
  const int ng8 = (t >> 5) * 8;
  float acc[8][4];
#pragma unroll
  for (int j = 0; j < 8; ++j)
#pragma unroll
    for (int c = 0; c < 4; ++c) acc[j][c] = 0.f;
#pragma unroll 8
  for (int k = 0; k < CC; ++k) {
    const float4 wv = *(const float4*)(W + k * CC + cg * 4);
#pragma unroll
    for (int j = 0; j < 8; ++j) {
      const float xv = xsT[k][ng8 + j];
      acc[j][0] = fmaf(xv, wv.x, acc[j][0]);
      acc[j][1] = fmaf(xv, wv.y, acc[j][1]);
      acc[j][2] = fmaf(xv, wv.z, acc[j][2]);
      acc[j][3] = fmaf(xv, wv.w, acc[j][3]);
    }
  }
  const float4 bb = *(const float4*)(bias + cg * 4);
  const float4 gg = *(const float4*)(gamma + cg * 4);
  const float4 bt = *(const float4*)(beta + cg * 4);
  const float4 mu = *(const float4*)(rmean + cg * 4);
  const float4 vr = *(const float4*)(rvar + cg * 4);
  float sc[4], sh[4];
  sc[0] = gg.x * rsqrtf(vr.x + BN_EPS);
  sc[1] = gg.y * rsqrtf(vr.y + BN_EPS);
  sc[2] = gg.z * rsqrtf(vr.z + BN_EPS);
  sc[3] = gg.w * rsqrtf(vr.w + BN_EPS);
  sh[0] = bt.x - mu.x * sc[0];
  sh[1] = bt.y - mu.y * sc[1];
  sh[2] = bt.z - mu.z * sc[2];
  sh[3] = bt.w - mu.w * sc[3];
#pragma unroll
  for (int j = 0; j < 8; ++j) {
    const int n = n0 + ng8 + j;
    if (n >= NN) continue;
    const int cn = cnt[n];
    const float inv = cn > 0 ? 1.0f / (float)cn : 0.0f;
    const float bsel = cn > 0 ? 1.0f : 0.0f;
    float4 o;
    o.x = fmaxf(0.f, (acc[j][0] * inv + bsel * bb.x) * sc[0] + sh[0]);
    o.y = fmaxf(0.f, (acc[j][1] * inv + bsel * bb.y) * sc[1] + sh[1]);
    o.z = fmaxf(0.f, (acc[j][2] * inv + bsel * bb.z) * sc[2] + sh[2]);
    o.w = fmaxf(0.f, (acc[j][3] * inv + bsel * bb.w) * sc[3] + sh[3]);
    *(float4*)(buf + (size_t)n * CC + cg * 4) = o;
  }
}

extern "C" void kernel_launch(void* const* d_in, const int* in_sizes, int n_in,
                              void* d_out, int out_size, void* d_ws, size_t ws_size,
                              hipStream_t stream) {
  const float* x     = (const float*)d_in[0];
  const int*   ei    = (const int*)d_in[1];
  const float* W     = (const float*)d_in[2];
  const float* bias  = (const float*)d_in[3];
  const float* gamma = (const float*)d_in[4];
  const float* beta  = (const float*)d_in[5];
  const float* rmean = (const float*)d_in[6];
  const float* rvar  = (const float*)d_in[7];
  float* out = (float*)d_out;

  // ws layout (bytes): off[NN+1] | cur[NN] | bsum[512] | csr[NE] | scsh[384f]
  //                    | Wsw[16384 bf16] | h[NN*CC bf16]
  const size_t OFF_B  = 0;
  const size_t CUR_B  = 400128;
  const size_t BSUM_B = 800256;
  const size_t CSR_B  = 802304;
  const size_t SCSH_B = 7202304;
  const size_t WSW_B  = 7204352;
  const size_t H_B    = 7237120;
  const size_t NEED   = H_B + (size_t)NN * CC * 2;  // ~32.8 MB

  if (ws_size >= NEED) {
    int*   off  = (int*)((char*)d_ws + OFF_B);
    int*   cur  = (int*)((char*)d_ws + CUR_B);
    int*   bsum = (int*)((char*)d_ws + BSUM_B);
    int*   csr  = (int*)((char*)d_ws + CSR_B);
    float* scsh = (float*)((char*)d_ws + SCSH_B);
    short* Wsw  = (short*)((char*)d_ws + WSW_B);
    short* h    = (short*)((char*)d_ws + H_B);

    prep_zero<<<NB, 256, 0, stream>>>(W, bias, gamma, beta, rmean, rvar,
                                      Wsw, scsh, cur);
    degree_count<<<(NE + 255) / 256, 256, 0, stream>>>(ei, cur);
    linear_mfma<<<LBLK, 256, 0, stream>>>(x, Wsw, scsh, h);
    scan1<<<NB, 256, 0, stream>>>(cur, off, bsum);
    scan3m<<<NB, 256, 0, stream>>>(off, bsum, cur);
    csr_fill_part<<<FCHUNKS * 8, 256, 0, stream>>>(ei, cur, csr);
    gather_bn_relu<<<GCH * 8, 256, 0, stream>>>(h, off, csr, scsh, out);
  } else {
    int* cnt = (int*)d_ws;
    hipMemsetAsync(out, 0, (size_t)NN * CC * sizeof(float), stream);
    hipMemsetAsync(cnt, 0, (size_t)NN * sizeof(int), stream);
    edge_scatter<<<(NE * 32) / 256, 256, 0, stream>>>(x, ei, out, cnt);
    gemm_bn_relu_fb<<<(NN + 63) / 64, 256, 0, stream>>>(
        out, W, bias, gamma, beta, rmean, rvar, cnt);
  }
}

// Round 7
// 339.109 us; speedup vs baseline: 2.3904x; 2.3904x over previous
//
#include <hip/hip_runtime.h>

// GCN layer on MI355X — round 7 (recover from r6 regression).
//   prep_zero:      Wsw (bf16 MFMA-B swizzle, column-permuted so lane m's 8
//                   accumulators are natural cols m*8..m*8+7), natural BN
//                   scale/shift + bias, cur=0
//   degree_count:   histogram of dst
//   linear_mfma:    h = bf16(x@W+b), natural channel order, coalesced stores
//   scan1/scan3m:   exclusive scan -> off (+cursor copy)
//   csr_fill_part:  XCD-partitioned fill (r4 win)
//   gather_bn_relu: r5 structure (one wave per dst node, full 256B row read
//                   per edge — best measured: 88.5us, FETCH 179MB ~= the
//                   per-XCD compulsory-stream floor), now with natural h
//                   (no LDS un-permute) and 8-deep edge unroll for 2x MLP
//                   on the dependent csr->h chain.
// r6 lesson: channel-split per XCD fetched 743MB (line sharing across XCDs +
// blockIdx->XCD mapping not reliable for short blocks) — do not retry.
// mean(h[src]) = mean(x[src])@W + b (linearity); deg=0 -> sum=0 -> relu(sh).

#define NN 100000
#define NE 1600000
#define CC 128
#define BN_EPS 1e-5f
#define NB 391        // ceil(NN/256)
#define LBLK 1563     // ceil(NN/64) linear blocks
#define FCHUNKS 256   // csr_fill chunks per partition
#define FCHUNK 6250   // 256*6250 = NE
#define PARTN 12500   // NN/8 dst nodes per XCD partition
#define LSTR 136      // LDS row stride in bf16 (128 + 8 pad)

typedef __attribute__((ext_vector_type(8))) short bf16x8;
typedef __attribute__((ext_vector_type(4))) float f32x4;

static __device__ __forceinline__ short f2bf(float f) {
  union { float f; unsigned u; } v; v.f = f;
  unsigned r = (v.u + 0x7FFF + ((v.u >> 16) & 1)) >> 16;  // RNE
  return (short)r;
}
static __device__ __forceinline__ float bflo(unsigned p) {
  return __uint_as_float(p << 16);
}
static __device__ __forceinline__ float bfhi(unsigned p) {
  return __uint_as_float(p & 0xffff0000u);
}

// ---------------------------------------------------------------------------
// prep_zero: zero cursor; swizzle W into bf16 B-fragments with the column
// permutation col(nt,m) = m*8+nt; natural-order BN scale/shift and bias.
// B-frag (16x16x32): lane = mslot + 16*quad holds B[kb*32+quad*8+j][col].
// ---------------------------------------------------------------------------
__global__ __launch_bounds__(256) void prep_zero(
    const float* __restrict__ W, const float* __restrict__ bias,
    const float* __restrict__ gamma, const float* __restrict__ beta,
    const float* __restrict__ rmean, const float* __restrict__ rvar,
    short* __restrict__ Wsw, float* __restrict__ scsh,
    int* __restrict__ cur) {
  const int i = blockIdx.x * 256 + threadIdx.x;
  if (i < NN) cur[i] = 0;
  if (i < CC * CC) {
    const int k = i >> 7, n = i & 127;
    const int nt = n & 7, m = n >> 3;  // col n -> tile nt, slot m
    const int kb = k >> 5, q = (k >> 3) & 3, j = k & 7;
    Wsw[(size_t)(((nt * 4 + kb) * 64 + (m + 16 * q)) * 8 + j)] = f2bf(W[i]);
  }
  if (i < CC) {
    const float sc = gamma[i] * rsqrtf(rvar[i] + BN_EPS);
    scsh[i] = sc;
    scsh[CC + i] = beta[i] - rmean[i] * sc;
    scsh[2 * CC + i] = bias[i];
  }
}

// ---------------------------------------------------------------------------
// degree_count: 1.6M int atomics.
// ---------------------------------------------------------------------------
__global__ __launch_bounds__(256) void degree_count(const int* __restrict__ ei,
                                                    int* __restrict__ cnt) {
  int e = blockIdx.x * 256 + threadIdx.x;
  if (e >= NE) return;
  atomicAdd(cnt + ei[NE + e], 1);
}

// ---------------------------------------------------------------------------
// linear_mfma: h = bf16(x@W+b), 64 rows/block, 4 waves x 16 rows.
// LDS-staged coalesced loads; MFMA with permuted-column Wsw; lane m's 8
// accumulators = natural cols m*8..+7 -> one bf16x8 coalesced store per row.
// ---------------------------------------------------------------------------
__global__ __launch_bounds__(256) void linear_mfma(
    const float* __restrict__ x, const short* __restrict__ Wsw,
    const float* __restrict__ scsh, short* __restrict__ hout) {
  __shared__ short lsA[64 * LSTR];  // 17.4 KB
  const int t = threadIdx.x;
  const int n0 = blockIdx.x * 64;

#pragma unroll
  for (int j = 0; j < 8; ++j) {
    const int idx = j * 256 + t;
    const int row = idx >> 5, kc4 = idx & 31;
    float4 v = make_float4(0.f, 0.f, 0.f, 0.f);
    if (n0 + row < NN) v = *(const float4*)(x + (size_t)(n0 + row) * CC + kc4 * 4);
    short4 s;
    s.x = f2bf(v.x); s.y = f2bf(v.y); s.z = f2bf(v.z); s.w = f2bf(v.w);
    *(short4*)(lsA + row * LSTR + kc4 * 4) = s;
  }
  __syncthreads();

  const int wave = t >> 6, lane = t & 63;
  const int quad = lane >> 4, m = lane & 15;
  const int rowbase = n0 + wave * 16;

  f32x4 acc[8];
#pragma unroll
  for (int nt = 0; nt < 8; ++nt) acc[nt] = (f32x4){0.f, 0.f, 0.f, 0.f};

#pragma unroll
  for (int kb = 0; kb < 4; ++kb) {
    const bf16x8 a =
        *(const bf16x8*)(lsA + (wave * 16 + m) * LSTR + kb * 32 + quad * 8);
#pragma unroll
    for (int nt = 0; nt < 8; ++nt) {
      bf16x8 b = *(const bf16x8*)(Wsw + (size_t)(((nt * 4 + kb) * 64 + lane) * 8));
      acc[nt] = __builtin_amdgcn_mfma_f32_16x16x32_bf16(a, b, acc[nt], 0, 0, 0);
    }
  }

  const float4 b0 = *(const float4*)(scsh + 2 * CC + m * 8);
  const float4 b1 = *(const float4*)(scsh + 2 * CC + m * 8 + 4);
  const float bv[8] = {b0.x, b0.y, b0.z, b0.w, b1.x, b1.y, b1.z, b1.w};

#pragma unroll
  for (int reg = 0; reg < 4; ++reg) {
    const int R = rowbase + quad * 4 + reg;
    if (R >= NN) continue;
    bf16x8 hv;
#pragma unroll
    for (int nt = 0; nt < 8; ++nt) hv[nt] = f2bf(acc[nt][reg] + bv[nt]);
    *(bf16x8*)(hout + (size_t)R * CC + m * 8) = hv;  // natural, 16B coalesced
  }
}

// ---------------------------------------------------------------------------
// scan1 / scan3m: exclusive scan -> off (+cursor copy).
// ---------------------------------------------------------------------------
__global__ __launch_bounds__(256) void scan1(const int* __restrict__ cnt,
                                             int* __restrict__ off,
                                             int* __restrict__ bsum) {
  __shared__ int sh[256];
  const int t = threadIdx.x;
  const int i = blockIdx.x * 256 + t;
  const int v = (i < NN) ? cnt[i] : 0;
  sh[t] = v;
  __syncthreads();
  for (int d = 1; d < 256; d <<= 1) {
    int add = (t >= d) ? sh[t - d] : 0;
    __syncthreads();
    sh[t] += add;
    __syncthreads();
  }
  if (i < NN) off[i] = sh[t] - v;
  if (t == 255) bsum[blockIdx.x] = sh[t];
}

__global__ __launch_bounds__(256) void scan3m(int* __restrict__ off,
                                              const int* __restrict__ bsum,
                                              int* __restrict__ cur) {
  __shared__ int sh[256];
  const int b = blockIdx.x, t = threadIdx.x;
  int s = 0;
  for (int j = t; j < b; j += 256) s += bsum[j];
  sh[t] = s;
  __syncthreads();
  for (int d = 128; d > 0; d >>= 1) {
    if (t < d) sh[t] += sh[t + d];
    __syncthreads();
  }
  const int pref = sh[0];
  const int i = b * 256 + t;
  if (i < NN) {
    int o = off[i] + pref;
    off[i] = o;
    cur[i] = o;
  }
  if (i == 0) off[NN] = NE;
}

// ---------------------------------------------------------------------------
// csr_fill, XCD-partitioned (r4 win).
// ---------------------------------------------------------------------------
__global__ __launch_bounds__(256) void csr_fill_part(
    const int* __restrict__ ei, int* __restrict__ cursor,
    int* __restrict__ csr) {
  const int p = blockIdx.x & 7;
  const int c = blockIdx.x >> 3;
  const int lo = p * PARTN, hi = lo + PARTN;
  const int e0 = c * FCHUNK;
  const int e1 = e0 + FCHUNK;
  for (int e = e0 + threadIdx.x; e < e1; e += 256) {
    int dst = ei[NE + e];
    if (dst >= lo && dst < hi) {
      int pos = atomicAdd(cursor + dst, 1);
      csr[pos] = ei[e];
    }
  }
}

// ---------------------------------------------------------------------------
// gather_bn_relu (r5 structure, natural h): one wave per dst node; lane owns
// uint col = lane (channels 2l,2l+1) -> one contiguous 256B row read per
// edge. 8-deep edge unroll for 2x MLP on the dependent csr->h chain.
// ---------------------------------------------------------------------------
__global__ __launch_bounds__(256) void gather_bn_relu(
    const short* __restrict__ h, const int* __restrict__ off,
    const int* __restrict__ csr, const float* __restrict__ scsh,
    float* __restrict__ out) {
  const int node = (blockIdx.x * 256 + threadIdx.x) >> 6;
  const int lane = threadIdx.x & 63;
  if (node >= NN) return;
  const int s = off[node], e = off[node + 1];
  const unsigned* hb = (const unsigned*)h;

  float ax = 0.f, ay = 0.f;
  int i = s;
  for (; i + 7 < e; i += 8) {
    const int s0 = csr[i + 0], s1 = csr[i + 1], s2 = csr[i + 2], s3 = csr[i + 3];
    const int s4 = csr[i + 4], s5 = csr[i + 5], s6 = csr[i + 6], s7 = csr[i + 7];
    const unsigned p0 = hb[(size_t)s0 * 64 + lane];
    const unsigned p1 = hb[(size_t)s1 * 64 + lane];
    const unsigned p2 = hb[(size_t)s2 * 64 + lane];
    const unsigned p3 = hb[(size_t)s3 * 64 + lane];
    const unsigned p4 = hb[(size_t)s4 * 64 + lane];
    const unsigned p5 = hb[(size_t)s5 * 64 + lane];
    const unsigned p6 = hb[(size_t)s6 * 64 + lane];
    const unsigned p7 = hb[(size_t)s7 * 64 + lane];
    ax += ((bflo(p0) + bflo(p1)) + (bflo(p2) + bflo(p3))) +
          ((bflo(p4) + bflo(p5)) + (bflo(p6) + bflo(p7)));
    ay += ((bfhi(p0) + bfhi(p1)) + (bfhi(p2) + bfhi(p3))) +
          ((bfhi(p4) + bfhi(p5)) + (bfhi(p6) + bfhi(p7)));
  }
  for (; i + 3 < e; i += 4) {
    const int s0 = csr[i + 0], s1 = csr[i + 1], s2 = csr[i + 2], s3 = csr[i + 3];
    const unsigned p0 = hb[(size_t)s0 * 64 + lane];
    const unsigned p1 = hb[(size_t)s1 * 64 + lane];
    const unsigned p2 = hb[(size_t)s2 * 64 + lane];
    const unsigned p3 = hb[(size_t)s3 * 64 + lane];
    ax += (bflo(p0) + bflo(p1)) + (bflo(p2) + bflo(p3));
    ay += (bfhi(p0) + bfhi(p1)) + (bfhi(p2) + bfhi(p3));
  }
  for (; i < e; ++i) {
    const unsigned p = hb[(size_t)csr[i] * 64 + lane];
    ax += bflo(p);
    ay += bfhi(p);
  }
  const float inv = (e > s) ? 1.0f / (float)(e - s) : 0.0f;
  const float2 sc = *(const float2*)(scsh + 2 * lane);
  const float2 sh = *(const float2*)(scsh + CC + 2 * lane);
  float2 o;
  o.x = fmaxf(0.f, ax * inv * sc.x + sh.x);
  o.y = fmaxf(0.f, ay * inv * sc.y + sh.y);
  *(float2*)(out + (size_t)node * CC + lane * 2) = o;
}

// ---------------------------------------------------------------------------
// Fallback (small ws): atomic scatter + fp32 vector GEMM.
// ---------------------------------------------------------------------------
__global__ __launch_bounds__(256) void edge_scatter(
    const float* __restrict__ x, const int* __restrict__ ei,
    float* __restrict__ sums, int* __restrict__ cnt) {
  int gt = blockIdx.x * 256 + threadIdx.x;
  int e = gt >> 5;
  int sub = gt & 31;
  if (e >= NE) return;
  int src = ei[e];
  int dst = ei[NE + e];
  const float4 v = *(const float4*)(x + (size_t)src * CC + sub * 4);
  float* o = sums + (size_t)dst * CC + sub * 4;
  unsafeAtomicAdd(o + 0, v.x);
  unsafeAtomicAdd(o + 1, v.y);
  unsafeAtomicAdd(o + 2, v.z);
  unsafeAtomicAdd(o + 3, v.w);
  if (sub == 0) atomicAdd(cnt + dst, 1);
}

__global__ __launch_bounds__(256) void gemm_bn_relu_fb(
    float* buf, const float* __restrict__ W, const float* __restrict__ bias,
    const float* __restrict__ gamma, const float* __restrict__ beta,
    const float* __restrict__ rmean, const float* __restrict__ rvar,
    const int* __restrict__ cnt) {
  __shared__ float xsT[CC][65];
  const int t = threadIdx.x;
  const int n0 = blockIdx.x * 64;
  for (int j = 0; j < 8; ++j) {
    int i = t + 256 * j;
    int row = i >> 5;
    int ko = (i & 31) * 4;
    float4 v = make_float4(0.f, 0.f, 0.f, 0.f);
    if (n0 + row < NN) v = *(const float4*)(buf + (size_t)(n0 + row) * CC + ko);
    xsT[ko + 0][row] = v.x;
    xsT[ko + 1][row] = v.y;
    xsT[ko + 2][row] = v.z;
    xsT[ko + 3][row] = v.w;
  }
  __syncthreads();
  const int cg = t & 31;
  const int ng8 = (t >> 5) * 8;
  float acc[8][4];
#pragma unroll
  for (int j = 0; j < 8; ++j)
#pragma unroll
    for (int c = 0; c < 4; ++c) acc[j][c] = 0.f;
#pragma unroll 8
  for (int k = 0; k < CC; ++k) {
    const float4 wv = *(const float4*)(W + k * CC + cg * 4);
#pragma unroll
    for (int j = 0; j < 8; ++j) {
      const float xv = xsT[k][ng8 + j];
      acc[j][0] = fmaf(xv, wv.x, acc[j][0]);
      acc[j][1] = fmaf(xv, wv.y, acc[j][1]);
      acc[j][2] = fmaf(xv, wv.z, acc[j][2]);
      acc[j][3] = fmaf(xv, wv.w, acc[j][3]);
    }
  }
  const float4 bb = *(const float4*)(bias + cg * 4);
  const float4 gg = *(const float4*)(gamma + cg * 4);
  const float4 bt = *(const float4*)(beta + cg * 4);
  const float4 mu = *(const float4*)(rmean + cg * 4);
  const float4 vr = *(const float4*)(rvar + cg * 4);
  float sc[4], sh[4];
  sc[0] = gg.x * rsqrtf(vr.x + BN_EPS);
  sc[1] = gg.y * rsqrtf(vr.y + BN_EPS);
  sc[2] = gg.z * rsqrtf(vr.z + BN_EPS);
  sc[3] = gg.w * rsqrtf(vr.w + BN_EPS);
  sh[0] = bt.x - mu.x * sc[0];
  sh[1] = bt.y - mu.y * sc[1];
  sh[2] = bt.z - mu.z * sc[2];
  sh[3] = bt.w - mu.w * sc[3];
#pragma unroll
  for (int j = 0; j < 8; ++j) {
    const int n = n0 + ng8 + j;
    if (n >= NN) continue;
    const int cn = cnt[n];
    const float inv = cn > 0 ? 1.0f / (float)cn : 0.0f;
    const float bsel = cn > 0 ? 1.0f : 0.0f;
    float4 o;
    o.x = fmaxf(0.f, (acc[j][0] * inv + bsel * bb.x) * sc[0] + sh[0]);
    o.y = fmaxf(0.f, (acc[j][1] * inv + bsel * bb.y) * sc[1] + sh[1]);
    o.z = fmaxf(0.f, (acc[j][2] * inv + bsel * bb.z) * sc[2] + sh[2]);
    o.w = fmaxf(0.f, (acc[j][3] * inv + bsel * bb.w) * sc[3] + sh[3]);
    *(float4*)(buf + (size_t)n * CC + cg * 4) = o;
  }
}

extern "C" void kernel_launch(void* const* d_in, const int* in_sizes, int n_in,
                              void* d_out, int out_size, void* d_ws, size_t ws_size,
                              hipStream_t stream) {
  const float* x     = (const float*)d_in[0];
  const int*   ei    = (const int*)d_in[1];
  const float* W     = (const float*)d_in[2];
  const float* bias  = (const float*)d_in[3];
  const float* gamma = (const float*)d_in[4];
  const float* beta  = (const float*)d_in[5];
  const float* rmean = (const float*)d_in[6];
  const float* rvar  = (const float*)d_in[7];
  float* out = (float*)d_out;

  // ws layout (bytes): off[NN+1] | cur[NN] | bsum[512] | csr[NE] | scsh[384f]
  //                    | Wsw[16384 bf16] | h[NN*CC bf16]
  const size_t OFF_B  = 0;
  const size_t CUR_B  = 400128;
  const size_t BSUM_B = 800256;
  const size_t CSR_B  = 802304;
  const size_t SCSH_B = 7202304;
  const size_t WSW_B  = 7204352;
  const size_t H_B    = 7237120;
  const size_t NEED   = H_B + (size_t)NN * CC * 2;  // ~32.8 MB

  if (ws_size >= NEED) {
    int*   off  = (int*)((char*)d_ws + OFF_B);
    int*   cur  = (int*)((char*)d_ws + CUR_B);
    int*   bsum = (int*)((char*)d_ws + BSUM_B);
    int*   csr  = (int*)((char*)d_ws + CSR_B);
    float* scsh = (float*)((char*)d_ws + SCSH_B);
    short* Wsw  = (short*)((char*)d_ws + WSW_B);
    short* h    = (short*)((char*)d_ws + H_B);

    prep_zero<<<NB, 256, 0, stream>>>(W, bias, gamma, beta, rmean, rvar,
                                      Wsw, scsh, cur);
    degree_count<<<(NE + 255) / 256, 256, 0, stream>>>(ei, cur);
    linear_mfma<<<LBLK, 256, 0, stream>>>(x, Wsw, scsh, h);
    scan1<<<NB, 256, 0, stream>>>(cur, off, bsum);
    scan3m<<<NB, 256, 0, stream>>>(off, bsum, cur);
    csr_fill_part<<<FCHUNKS * 8, 256, 0, stream>>>(ei, cur, csr);
    gather_bn_relu<<<(NN * 64 + 255) / 256, 256, 0, stream>>>(h, off, csr,
                                                              scsh, out);
  } else {
    int* cnt = (int*)d_ws;
    hipMemsetAsync(out, 0, (size_t)NN * CC * sizeof(float), stream);
    hipMemsetAsync(cnt, 0, (size_t)NN * sizeof(int), stream);
    edge_scatter<<<(NE * 32) / 256, 256, 0, stream>>>(x, ei, out, cnt);
    gemm_bn_relu_fb<<<(NN + 63) / 64, 256, 0, stream>>>(
        out, W, bias, gamma, beta, rmean, rvar, cnt);
  }
}

// Round 8
// 244.198 us; speedup vs baseline: 3.3195x; 1.3887x over previous
//
#include <hip/hip_runtime.h>

// GCN layer on MI355X — round 8.
// Pipeline: prep -> bucket_hist -> bucket_scan -> bucket_scatter(ebuf)
//           -> bucket_to_csr(off+csr) -> linear_mfma(h) -> gather_bn_relu.
// r7 lesson: cursor-based csr_fill had 11x partial-line write amplification
// (75MB for 6.4MB csr) because random 4B writes to one line arrive from many
// XCDs (blockIdx&7->XCD mapping unreliable — r6/r7 evidence). Fix: two-level
// bucket sort where EVERY global write is a coalesced sequential run
// (Phase A: LDS-sorted 4096-edge chunks -> per-bucket contiguous runs;
// Phase B: per-bucket LDS csr segment -> coalesced copy-out). Phase B also
// derives off[] from its local histogram, killing degree_count+scan kernels.
// ebuf aliases h (Phase B finishes before linear writes h) -> ws NEED
// unchanged at 32,837,120 B.
// mean(h[src]) = mean(x[src])@W + b (linearity); deg=0 -> sum=0 -> relu(sh).

#define NN 100000
#define NE 1600000
#define CC 128
#define BN_EPS 1e-5f
#define LBLK 1563     // ceil(NN/64) linear blocks
#define LSTR 136      // LDS row stride in bf16 (128 + 8 pad)
#define NBUK 256      // dst buckets
#define DPB 391       // dsts per bucket (256*391 = 100096 >= NN)
#define ACH 4096      // edges per Phase-A block
#define ABLK 391      // ceil(NE/ACH)
#define CAP 10240     // Phase-B LDS csr segment capacity (mean 6256, sigma~79)

typedef __attribute__((ext_vector_type(8))) short bf16x8;
typedef __attribute__((ext_vector_type(4))) float f32x4;

static __device__ __forceinline__ short f2bf(float f) {
  union { float f; unsigned u; } v; v.f = f;
  unsigned r = (v.u + 0x7FFF + ((v.u >> 16) & 1)) >> 16;  // RNE
  return (short)r;
}
static __device__ __forceinline__ float bflo(unsigned p) {
  return __uint_as_float(p << 16);
}
static __device__ __forceinline__ float bfhi(unsigned p) {
  return __uint_as_float(p & 0xffff0000u);
}

// ---------------------------------------------------------------------------
// prep_zero: zero bucket hist; swizzle W into bf16 MFMA-B fragments with the
// column permutation col(nt,m)=m*8+nt (D-lane m holds natural cols m*8..+7);
// natural-order BN scale/shift + bias.  64 blocks x 256 = 16384 = CC*CC.
// ---------------------------------------------------------------------------
__global__ __launch_bounds__(256) void prep_zero(
    const float* __restrict__ W, const float* __restrict__ bias,
    const float* __restrict__ gamma, const float* __restrict__ beta,
    const float* __restrict__ rmean, const float* __restrict__ rvar,
    short* __restrict__ Wsw, float* __restrict__ scsh,
    int* __restrict__ bhist) {
  const int i = blockIdx.x * 256 + threadIdx.x;
  if (i < NBUK) bhist[i] = 0;
  if (i < CC * CC) {
    const int k = i >> 7, n = i & 127;
    const int nt = n & 7, m = n >> 3;
    const int kb = k >> 5, q = (k >> 3) & 3, j = k & 7;
    Wsw[(size_t)(((nt * 4 + kb) * 64 + (m + 16 * q)) * 8 + j)] = f2bf(W[i]);
  }
  if (i < CC) {
    const float sc = gamma[i] * rsqrtf(rvar[i] + BN_EPS);
    scsh[i] = sc;
    scsh[CC + i] = beta[i] - rmean[i] * sc;
    scsh[2 * CC + i] = bias[i];
  }
}

// ---------------------------------------------------------------------------
// bucket_hist: per-block LDS histogram of dst buckets, then 256 global adds.
// ---------------------------------------------------------------------------
__global__ __launch_bounds__(256) void bucket_hist(const int* __restrict__ ei,
                                                   int* __restrict__ bhist) {
  __shared__ int lh[NBUK];
  const int t = threadIdx.x;
  lh[t] = 0;
  __syncthreads();
  const int e0 = blockIdx.x * ACH;
  const int e1 = min(NE, e0 + ACH);
  for (int e = e0 + t; e < e1; e += 256) atomicAdd(&lh[ei[NE + e] / DPB], 1);
  __syncthreads();
  if (lh[t]) atomicAdd(&bhist[t], lh[t]);
}

// ---------------------------------------------------------------------------
// bucket_scan: exclusive scan of the 256 bucket totals -> bbase, gcur.
// ---------------------------------------------------------------------------
__global__ __launch_bounds__(256) void bucket_scan(
    const int* __restrict__ bhist, int* __restrict__ bbase,
    int* __restrict__ gcur) {
  __shared__ int s[NBUK];
  const int t = threadIdx.x;
  const int v = bhist[t];
  s[t] = v;
  __syncthreads();
  for (int d = 1; d < 256; d <<= 1) {
    int a = (t >= d) ? s[t - d] : 0;
    __syncthreads();
    s[t] += a;
    __syncthreads();
  }
  const int ex = s[t] - v;
  bbase[t] = ex;
  gcur[t] = ex;
  if (t == 255) bbase[256] = NE;
}

// ---------------------------------------------------------------------------
// bucket_scatter (Phase A): sort a 4096-edge chunk by bucket in LDS, reserve
// one contiguous run per bucket in ebuf, write runs coalesced (sequential
// near-full-line stores — no partial-line RMW by construction).
// ---------------------------------------------------------------------------
__global__ __launch_bounds__(256) void bucket_scatter(
    const int* __restrict__ ei, int* __restrict__ gcur,
    int2* __restrict__ ebuf) {
  __shared__ int lh[NBUK], lbase[NBUK], lgb[NBUK], lc[NBUK];
  __shared__ int2 sorted[ACH];  // 32 KB
  const int t = threadIdx.x;
  const int e0 = blockIdx.x * ACH;
  const int e1 = min(NE, e0 + ACH);

  lh[t] = 0;
  __syncthreads();
  for (int e = e0 + t; e < e1; e += 256) atomicAdd(&lh[ei[NE + e] / DPB], 1);
  __syncthreads();

  // inclusive scan of lh into lbase, then convert to exclusive
  lbase[t] = lh[t];
  __syncthreads();
  for (int d = 1; d < 256; d <<= 1) {
    int a = (t >= d) ? lbase[t - d] : 0;
    __syncthreads();
    lbase[t] += a;
    __syncthreads();
  }
  const int excl = lbase[t] - lh[t];
  __syncthreads();
  lbase[t] = excl;
  lc[t] = excl;
  if (lh[t] > 0) lgb[t] = atomicAdd(&gcur[t], lh[t]);
  __syncthreads();

  for (int e = e0 + t; e < e1; e += 256) {
    const int src = ei[e], dst = ei[NE + e];
    const int b = dst / DPB;
    const int p = atomicAdd(&lc[b], 1);
    sorted[p] = make_int2(src, dst);
  }
  __syncthreads();

  const int n = e1 - e0;
  for (int i = t; i < n; i += 256) {
    const int2 v = sorted[i];
    const int b = v.y / DPB;
    ebuf[lgb[b] + (i - lbase[b])] = v;  // sequential within each run
  }
}

// ---------------------------------------------------------------------------
// bucket_to_csr (Phase B): one block per bucket. Per-dst histogram + scan in
// LDS -> writes off[] directly; scatters srcs into an LDS csr segment; copies
// out fully coalesced. Fallback to direct global scatter if seglen > CAP
// (statistically never for uniform dsts: mean 6256, CAP = mean + 50 sigma).
// ---------------------------------------------------------------------------
__global__ __launch_bounds__(256) void bucket_to_csr(
    const int2* __restrict__ ebuf, const int* __restrict__ bbase,
    int* __restrict__ off, int* __restrict__ csr) {
  __shared__ int dh[512];
  __shared__ int s[512];
  __shared__ int lcur[512];
  __shared__ int lcsr[CAP];  // 40 KB
  const int b = blockIdx.x, t = threadIdx.x;
  const int lo = b * DPB;
  const int hi = min(NN, lo + DPB);
  const int nd = hi - lo;
  const int segbase = bbase[b];
  const int seglen = bbase[b + 1] - segbase;
  const int2* eb = ebuf + segbase;

  for (int i = t; i < 512; i += 256) dh[i] = 0;
  __syncthreads();
  for (int i = t; i < seglen; i += 256) atomicAdd(&dh[eb[i].y - lo], 1);
  __syncthreads();

  // inclusive scan of dh[0..512) with 256 threads (2 elems/thread)
  for (int i = t; i < 512; i += 256) s[i] = dh[i];
  __syncthreads();
  for (int d = 1; d < 512; d <<= 1) {
    const int a0 = (t >= d) ? s[t - d] : 0;
    const int a1 = (t + 256 >= d) ? s[t + 256 - d] : 0;
    __syncthreads();
    s[t] += a0;
    s[t + 256] += a1;
    __syncthreads();
  }
  for (int i = t; i < 512; i += 256) lcur[i] = s[i] - dh[i];  // exclusive
  for (int d = t; d < nd; d += 256) off[lo + d] = segbase + (s[d] - dh[d]);
  if (b == NBUK - 1 && t == 0) off[NN] = NE;
  __syncthreads();

  if (seglen <= CAP) {
    for (int i = t; i < seglen; i += 256) {
      const int2 e = eb[i];
      const int p = atomicAdd(&lcur[e.y - lo], 1);
      lcsr[p] = e.x;
    }
    __syncthreads();
    for (int i = t; i < seglen; i += 256) csr[segbase + i] = lcsr[i];
  } else {
    for (int i = t; i < seglen; i += 256) {
      const int2 e = eb[i];
      const int p = atomicAdd(&lcur[e.y - lo], 1);
      csr[segbase + p] = e.x;
    }
  }
}

// ---------------------------------------------------------------------------
// linear_mfma: h = bf16(x@W+b), 64 rows/block, 4 waves x 16 rows.
// LDS-staged coalesced loads; MFMA with permuted-column Wsw; lane m's 8
// accumulators = natural cols m*8..+7 -> one bf16x8 coalesced store per row.
// Runs AFTER bucket_to_csr (h aliases ebuf).
// ---------------------------------------------------------------------------
__global__ __launch_bounds__(256) void linear_mfma(
    const float* __restrict__ x, const short* __restrict__ Wsw,
    const float* __restrict__ scsh, short* __restrict__ hout) {
  __shared__ short lsA[64 * LSTR];  // 17.4 KB
  const int t = threadIdx.x;
  const int n0 = blockIdx.x * 64;

#pragma unroll
  for (int j = 0; j < 8; ++j) {
    const int idx = j * 256 + t;
    const int row = idx >> 5, kc4 = idx & 31;
    float4 v = make_float4(0.f, 0.f, 0.f, 0.f);
    if (n0 + row < NN) v = *(const float4*)(x + (size_t)(n0 + row) * CC + kc4 * 4);
    short4 sv;
    sv.x = f2bf(v.x); sv.y = f2bf(v.y); sv.z = f2bf(v.z); sv.w = f2bf(v.w);
    *(short4*)(lsA + row * LSTR + kc4 * 4) = sv;
  }
  __syncthreads();

  const int wave = t >> 6, lane = t & 63;
  const int quad = lane >> 4, m = lane & 15;
  const int rowbase = n0 + wave * 16;

  f32x4 acc[8];
#pragma unroll
  for (int nt = 0; nt < 8; ++nt) acc[nt] = (f32x4){0.f, 0.f, 0.f, 0.f};

#pragma unroll
  for (int kb = 0; kb < 4; ++kb) {
    const bf16x8 a =
        *(const bf16x8*)(lsA + (wave * 16 + m) * LSTR + kb * 32 + quad * 8);
#pragma unroll
    for (int nt = 0; nt < 8; ++nt) {
      bf16x8 bb = *(const bf16x8*)(Wsw + (size_t)(((nt * 4 + kb) * 64 + lane) * 8));
      acc[nt] = __builtin_amdgcn_mfma_f32_16x16x32_bf16(a, bb, acc[nt], 0, 0, 0);
    }
  }

  const float4 b0 = *(const float4*)(scsh + 2 * CC + m * 8);
  const float4 b1 = *(const float4*)(scsh + 2 * CC + m * 8 + 4);
  const float bv[8] = {b0.x, b0.y, b0.z, b0.w, b1.x, b1.y, b1.z, b1.w};

#pragma unroll
  for (int reg = 0; reg < 4; ++reg) {
    const int R = rowbase + quad * 4 + reg;
    if (R >= NN) continue;
    bf16x8 hv;
#pragma unroll
    for (int nt = 0; nt < 8; ++nt) hv[nt] = f2bf(acc[nt][reg] + bv[nt]);
    *(bf16x8*)(hout + (size_t)R * CC + m * 8) = hv;
  }
}

// ---------------------------------------------------------------------------
// gather_bn_relu (r7 best): one wave per dst node; lane owns uint col = lane
// (channels 2l,2l+1) -> one contiguous 256B row read per edge; 8-deep edge
// unroll for MLP on the dependent csr->h chain.
// ---------------------------------------------------------------------------
__global__ __launch_bounds__(256) void gather_bn_relu(
    const short* __restrict__ h, const int* __restrict__ off,
    const int* __restrict__ csr, const float* __restrict__ scsh,
    float* __restrict__ out) {
  const int node = (blockIdx.x * 256 + threadIdx.x) >> 6;
  const int lane = threadIdx.x & 63;
  if (node >= NN) return;
  const int s = off[node], e = off[node + 1];
  const unsigned* hb = (const unsigned*)h;

  float ax = 0.f, ay = 0.f;
  int i = s;
  for (; i + 7 < e; i += 8) {
    const int s0 = csr[i + 0], s1 = csr[i + 1], s2 = csr[i + 2], s3 = csr[i + 3];
    const int s4 = csr[i + 4], s5 = csr[i + 5], s6 = csr[i + 6], s7 = csr[i + 7];
    const unsigned p0 = hb[(size_t)s0 * 64 + lane];
    const unsigned p1 = hb[(size_t)s1 * 64 + lane];
    const unsigned p2 = hb[(size_t)s2 * 64 + lane];
    const unsigned p3 = hb[(size_t)s3 * 64 + lane];
    const unsigned p4 = hb[(size_t)s4 * 64 + lane];
    const unsigned p5 = hb[(size_t)s5 * 64 + lane];
    const unsigned p6 = hb[(size_t)s6 * 64 + lane];
    const unsigned p7 = hb[(size_t)s7 * 64 + lane];
    ax += ((bflo(p0) + bflo(p1)) + (bflo(p2) + bflo(p3))) +
          ((bflo(p4) + bflo(p5)) + (bflo(p6) + bflo(p7)));
    ay += ((bfhi(p0) + bfhi(p1)) + (bfhi(p2) + bfhi(p3))) +
          ((bfhi(p4) + bfhi(p5)) + (bfhi(p6) + bfhi(p7)));
  }
  for (; i + 3 < e; i += 4) {
    const int s0 = csr[i + 0], s1 = csr[i + 1], s2 = csr[i + 2], s3 = csr[i + 3];
    const unsigned p0 = hb[(size_t)s0 * 64 + lane];
    const unsigned p1 = hb[(size_t)s1 * 64 + lane];
    const unsigned p2 = hb[(size_t)s2 * 64 + lane];
    const unsigned p3 = hb[(size_t)s3 * 64 + lane];
    ax += (bflo(p0) + bflo(p1)) + (bflo(p2) + bflo(p3));
    ay += (bfhi(p0) + bfhi(p1)) + (bfhi(p2) + bfhi(p3));
  }
  for (; i < e; ++i) {
    const unsigned p = hb[(size_t)csr[i] * 64 + lane];
    ax += bflo(p);
    ay += bfhi(p);
  }
  const float inv = (e > s) ? 1.0f / (float)(e - s) : 0.0f;
  const float2 sc = *(const float2*)(scsh + 2 * lane);
  const float2 sh = *(const float2*)(scsh + CC + 2 * lane);
  float2 o;
  o.x = fmaxf(0.f, ax * inv * sc.x + sh.x);
  o.y = fmaxf(0.f, ay * inv * sc.y + sh.y);
  *(float2*)(out + (size_t)node * CC + lane * 2) = o;
}

// ---------------------------------------------------------------------------
// Fallback (small ws): atomic scatter + fp32 vector GEMM.
// ---------------------------------------------------------------------------
__global__ __launch_bounds__(256) void edge_scatter(
    const float* __restrict__ x, const int* __restrict__ ei,
    float* __restrict__ sums, int* __restrict__ cnt) {
  int gt = blockIdx.x * 256 + threadIdx.x;
  int e = gt >> 5;
  int sub = gt & 31;
  if (e >= NE) return;
  int src = ei[e];
  int dst = ei[NE + e];
  const float4 v = *(const float4*)(x + (size_t)src * CC + sub * 4);
  float* o = sums + (size_t)dst * CC + sub * 4;
  unsafeAtomicAdd(o + 0, v.x);
  unsafeAtomicAdd(o + 1, v.y);
  unsafeAtomicAdd(o + 2, v.z);
  unsafeAtomicAdd(o + 3, v.w);
  if (sub == 0) atomicAdd(cnt + dst, 1);
}

__global__ __launch_bounds__(256) void gemm_bn_relu_fb(
    float* buf, const float* __restrict__ W, const float* __restrict__ bias,
    const float* __restrict__ gamma, const float* __restrict__ beta,
    const float* __restrict__ rmean, const float* __restrict__ rvar,
    const int* __restrict__ cnt) {
  __shared__ float xsT[CC][65];
  const int t = threadIdx.x;
  const int n0 = blockIdx.x * 64;
  for (int j = 0; j < 8; ++j) {
    int i = t + 256 * j;
    int row = i >> 5;
    int ko = (i & 31) * 4;
    float4 v = make_float4(0.f, 0.f, 0.f, 0.f);
    if (n0 + row < NN) v = *(const float4*)(buf + (size_t)(n0 + row) * CC + ko);
    xsT[ko + 0][row] = v.x;
    xsT[ko + 1][row] = v.y;
    xsT[ko + 2][row] = v.z;
    xsT[ko + 3][row] = v.w;
  }
  __syncthreads();
  const int cg = t & 31;
  const int ng8 = (t >> 5) * 8;
  float acc[8][4];
#pragma unroll
  for (int j = 0; j < 8; ++j)
#pragma unroll
    for (int c = 0; c < 4; ++c) acc[j][c] = 0.f;
#pragma unroll 8
  for (int k = 0; k < CC; ++k) {
    const float4 wv = *(const float4*)(W + k * CC + cg * 4);
#pragma unroll
    for (int j = 0; j < 8; ++j) {
      const float xv = xsT[k][ng8 + j];
      acc[j][0] = fmaf(xv, wv.x, acc[j][0]);
      acc[j][1] = fmaf(xv, wv.y, acc[j][1]);
      acc[j][2] = fmaf(xv, wv.z, acc[j][2]);
      acc[j][3] = fmaf(xv, wv.w, acc[j][3]);
    }
  }
  const float4 bb = *(const float4*)(bias + cg * 4);
  const float4 gg = *(const float4*)(gamma + cg * 4);
  const float4 bt = *(const float4*)(beta + cg * 4);
  const float4 mu = *(const float4*)(rmean + cg * 4);
  const float4 vr = *(const float4*)(rvar + cg * 4);
  float sc[4], sh[4];
  sc[0] = gg.x * rsqrtf(vr.x + BN_EPS);
  sc[1] = gg.y * rsqrtf(vr.y + BN_EPS);
  sc[2] = gg.z * rsqrtf(vr.z + BN_EPS);
  sc[3] = gg.w * rsqrtf(vr.w + BN_EPS);
  sh[0] = bt.x - mu.x * sc[0];
  sh[1] = bt.y - mu.y * sc[1];
  sh[2] = bt.z - mu.z * sc[2];
  sh[3] = bt.w - mu.w * sc[3];
#pragma unroll
  for (int j = 0; j < 8; ++j) {
    const int n = n0 + ng8 + j;
    if (n >= NN) continue;
    const int cn = cnt[n];
    const float inv = cn > 0 ? 1.0f / (float)cn : 0.0f;
    const float bsel = cn > 0 ? 1.0f : 0.0f;
    float4 o;
    o.x = fmaxf(0.f, (acc[j][0] * inv + bsel * bb.x) * sc[0] + sh[0]);
    o.y = fmaxf(0.f, (acc[j][1] * inv + bsel * bb.y) * sc[1] + sh[1]);
    o.z = fmaxf(0.f, (acc[j][2] * inv + bsel * bb.z) * sc[2] + sh[2]);
    o.w = fmaxf(0.f, (acc[j][3] * inv + bsel * bb.w) * sc[3] + sh[3]);
    *(float4*)(buf + (size_t)n * CC + cg * 4) = o;
  }
}

extern "C" void kernel_launch(void* const* d_in, const int* in_sizes, int n_in,
                              void* d_out, int out_size, void* d_ws, size_t ws_size,
                              hipStream_t stream) {
  const float* x     = (const float*)d_in[0];
  const int*   ei    = (const int*)d_in[1];
  const float* W     = (const float*)d_in[2];
  const float* bias  = (const float*)d_in[3];
  const float* gamma = (const float*)d_in[4];
  const float* beta  = (const float*)d_in[5];
  const float* rmean = (const float*)d_in[6];
  const float* rvar  = (const float*)d_in[7];
  float* out = (float*)d_out;

  // ws layout (bytes): off[NN+1] | bhist[256] | bbase[257] | gcur[256] | ...
  //                    csr[NE] | scsh[384f] | Wsw[16384 bf16] | h[NN*CC bf16]
  // ebuf (int2[NE], 12.8 MB) aliases the h region (dead before linear runs).
  const size_t OFF_B  = 0;
  const size_t BH_B   = 400128;
  const size_t BB_B   = 401152;
  const size_t GC_B   = 402304;
  const size_t CSR_B  = 802304;
  const size_t SCSH_B = 7202304;
  const size_t WSW_B  = 7204352;
  const size_t H_B    = 7237120;
  const size_t NEED   = H_B + (size_t)NN * CC * 2;  // 32,837,120

  if (ws_size >= NEED) {
    int*   off   = (int*)((char*)d_ws + OFF_B);
    int*   bhist = (int*)((char*)d_ws + BH_B);
    int*   bbase = (int*)((char*)d_ws + BB_B);
    int*   gcur  = (int*)((char*)d_ws + GC_B);
    int*   csr   = (int*)((char*)d_ws + CSR_B);
    float* scsh  = (float*)((char*)d_ws + SCSH_B);
    short* Wsw   = (short*)((char*)d_ws + WSW_B);
    short* h     = (short*)((char*)d_ws + H_B);
    int2*  ebuf  = (int2*)((char*)d_ws + H_B);  // alias

    prep_zero<<<64, 256, 0, stream>>>(W, bias, gamma, beta, rmean, rvar,
                                      Wsw, scsh, bhist);
    bucket_hist<<<ABLK, 256, 0, stream>>>(ei, bhist);
    bucket_scan<<<1, 256, 0, stream>>>(bhist, bbase, gcur);
    bucket_scatter<<<ABLK, 256, 0, stream>>>(ei, gcur, ebuf);
    bucket_to_csr<<<NBUK, 256, 0, stream>>>(ebuf, bbase, off, csr);
    linear_mfma<<<LBLK, 256, 0, stream>>>(x, Wsw, scsh, h);
    gather_bn_relu<<<(NN * 64 + 255) / 256, 256, 0, stream>>>(h, off, csr,
                                                              scsh, out);
  } else {
    int* cnt = (int*)d_ws;
    hipMemsetAsync(out, 0, (size_t)NN * CC * sizeof(float), stream);
    hipMemsetAsync(cnt, 0, (size_t)NN * sizeof(int), stream);
    edge_scatter<<<(NE * 32) / 256, 256, 0, stream>>>(x, ei, out, cnt);
    gemm_bn_relu_fb<<<(NN + 63) / 64, 256, 0, stream>>>(
        out, W, bias, gamma, beta, rmean, rvar, cnt);
  }
}

// Round 9
// 239.187 us; speedup vs baseline: 3.3891x; 1.0209x over previous
//
#include <hip/hip_runtime.h>

// GCN layer on MI355X — round 9: dispatch-count reduction (7 -> 5 graph nodes).
//   M1:  memsetAsync(bhist+gcurz, 0, 2KB)
//   K1 prep_hist:      Wsw swizzle + BN consts (blocks 0-63) FUSED with
//                      bucket histogram (all 391 blocks)
//   K2 scatter_linear: bucket_scatter (391 blocks) FUSED with linear_mfma
//                      (1563 blocks) — independent outputs, pipes overlap.
//                      bucket_scan kernel deleted: each consumer recomputes
//                      the 256-wide bhist scan in LDS (~1us).
//   K3 bucket_to_csr:  per-bucket LDS csr segment -> off + csr (coalesced)
//   K4 gather_bn_relu: r8-best gather (71.7us, FETCH 179MB ~= structural
//                      floor for bf16 h; fp8 would risk absmax ~0.02 vs
//                      0.0222 threshold — not taken)
// Fusion forces ebuf != h  -> NEED 45.6MB; tier-2 (ws >= 32.8MB, proven) runs
// the same kernels un-fused with ebuf aliasing h; atomic fallback last.
// mean(h[src]) = mean(x[src])@W + b (linearity); deg=0 -> sum=0 -> relu(sh).

#define NN 100000
#define NE 1600000
#define CC 128
#define BN_EPS 1e-5f
#define LBLK 1563     // ceil(NN/64) linear blocks
#define LSTR 136      // LDS row stride in bf16 (128 + 8 pad)
#define NBUK 256      // dst buckets
#define DPB 391       // dsts per bucket (256*391 = 100096 >= NN)
#define ACH 4096      // edges per scatter block
#define ABLK 391      // ceil(NE/ACH)
#define CAP 10240     // to_csr LDS segment capacity (mean 6250, huge margin)

typedef __attribute__((ext_vector_type(8))) short bf16x8;
typedef __attribute__((ext_vector_type(4))) float f32x4;

static __device__ __forceinline__ short f2bf(float f) {
  union { float f; unsigned u; } v; v.f = f;
  unsigned r = (v.u + 0x7FFF + ((v.u >> 16) & 1)) >> 16;  // RNE
  return (short)r;
}
static __device__ __forceinline__ float bflo(unsigned p) {
  return __uint_as_float(p << 16);
}
static __device__ __forceinline__ float bfhi(unsigned p) {
  return __uint_as_float(p & 0xffff0000u);
}

// 256-wide Hillis-Steele scan in LDS; leaves a[] exclusive, returns excl[t].
static __device__ __forceinline__ int excl_scan256(int* a, int t, int v) {
  a[t] = v;
  __syncthreads();
  for (int d = 1; d < 256; d <<= 1) {
    const int x = (t >= d) ? a[t - d] : 0;
    __syncthreads();
    a[t] += x;
    __syncthreads();
  }
  const int incl = a[t];
  __syncthreads();
  a[t] = incl - v;
  __syncthreads();
  return incl - v;
}

// ---------------------------------------------------------------------------
// K1: prep (Wsw swizzle, col-permuted so D-lane m holds natural cols m*8..+7;
// BN scale/shift + bias) on blocks 0-63, bucket histogram on all 391 blocks.
// bhist pre-zeroed by the M1 memset.
// ---------------------------------------------------------------------------
__global__ __launch_bounds__(256) void prep_hist(
    const float* __restrict__ W, const float* __restrict__ bias,
    const float* __restrict__ gamma, const float* __restrict__ beta,
    const float* __restrict__ rmean, const float* __restrict__ rvar,
    const int* __restrict__ ei, short* __restrict__ Wsw,
    float* __restrict__ scsh, int* __restrict__ bhist) {
  __shared__ int lh[NBUK];
  const int t = threadIdx.x;
  const int i = blockIdx.x * 256 + t;
  if (i < CC * CC) {
    const int k = i >> 7, n = i & 127;
    const int nt = n & 7, m = n >> 3;
    const int kb = k >> 5, q = (k >> 3) & 3, j = k & 7;
    Wsw[(size_t)(((nt * 4 + kb) * 64 + (m + 16 * q)) * 8 + j)] = f2bf(W[i]);
  }
  if (i < CC) {
    const float sc = gamma[i] * rsqrtf(rvar[i] + BN_EPS);
    scsh[i] = sc;
    scsh[CC + i] = beta[i] - rmean[i] * sc;
    scsh[2 * CC + i] = bias[i];
  }
  lh[t] = 0;
  __syncthreads();
  const int e0 = blockIdx.x * ACH;
  const int e1 = min(NE, e0 + ACH);
  for (int e = e0 + t; e < e1; e += 256) atomicAdd(&lh[ei[NE + e] / DPB], 1);
  __syncthreads();
  if (lh[t]) atomicAdd(&bhist[t], lh[t]);
}

// ---------------------------------------------------------------------------
// K2: blocks [0,scat): bucket_scatter — chunk-sort 4096 edges by bucket in
// LDS, reserve contiguous global runs (bhist-scan recomputed in LDS + gcurz
// atomics), write ebuf coalesced. blocks [scat,..): linear_mfma — h =
// bf16(x@W+b), LDS-staged, natural cols, bf16x8 stores. LDS unioned (37KB).
// ---------------------------------------------------------------------------
__global__ __launch_bounds__(256) void scatter_linear(
    const int* __restrict__ ei, const int* __restrict__ bhist,
    int* __restrict__ gcurz, int2* __restrict__ ebuf,
    const float* __restrict__ x, const short* __restrict__ Wsw,
    const float* __restrict__ scsh, short* __restrict__ hout,
    int scat) {
  __shared__ int2 sorted[ACH];  // 32 KB (linear role aliases as bf16 tile)
  __shared__ int gsc[NBUK], lh[NBUK], lex[NBUK], rb[NBUK], lc[NBUK];
  const int t = threadIdx.x;

  if (blockIdx.x < scat) {
    // ----- scatter role -----
    const int e0 = blockIdx.x * ACH;
    const int e1 = min(NE, e0 + ACH);
    // global bucket bases (exclusive scan of bhist)
    const int gbase = excl_scan256(gsc, t, bhist[t]);
    // chunk histogram
    lh[t] = 0;
    __syncthreads();
    for (int e = e0 + t; e < e1; e += 256) atomicAdd(&lh[ei[NE + e] / DPB], 1);
    __syncthreads();
    const int vh = lh[t];
    const int lbase = excl_scan256(lex, t, vh);
    lc[t] = lbase;
    if (vh > 0) rb[t] = gbase + atomicAdd(&gcurz[t], vh);
    __syncthreads();
    // sort chunk into LDS by bucket
    for (int e = e0 + t; e < e1; e += 256) {
      const int src = ei[e], dst = ei[NE + e];
      const int p = atomicAdd(&lc[dst / DPB], 1);
      sorted[p] = make_int2(src, dst);
    }
    __syncthreads();
    // write runs (sequential within each bucket run -> near-full lines)
    const int n = e1 - e0;
    for (int i = t; i < n; i += 256) {
      const int2 v = sorted[i];
      const int b = v.y / DPB;
      ebuf[rb[b] + (i - lex[b])] = v;
    }
    return;
  }

  // ----- linear role -----
  short* lsA = (short*)sorted;  // 64*LSTR*2 = 17.4 KB <= 32 KB
  const int n0 = (blockIdx.x - scat) * 64;

#pragma unroll
  for (int j = 0; j < 8; ++j) {
    const int idx = j * 256 + t;
    const int row = idx >> 5, kc4 = idx & 31;
    float4 v = make_float4(0.f, 0.f, 0.f, 0.f);
    if (n0 + row < NN) v = *(const float4*)(x + (size_t)(n0 + row) * CC + kc4 * 4);
    short4 sv;
    sv.x = f2bf(v.x); sv.y = f2bf(v.y); sv.z = f2bf(v.z); sv.w = f2bf(v.w);
    *(short4*)(lsA + row * LSTR + kc4 * 4) = sv;
  }
  __syncthreads();

  const int wave = t >> 6, lane = t & 63;
  const int quad = lane >> 4, m = lane & 15;
  const int rowbase = n0 + wave * 16;

  f32x4 acc[8];
#pragma unroll
  for (int nt = 0; nt < 8; ++nt) acc[nt] = (f32x4){0.f, 0.f, 0.f, 0.f};

#pragma unroll
  for (int kb = 0; kb < 4; ++kb) {
    const bf16x8 a =
        *(const bf16x8*)(lsA + (wave * 16 + m) * LSTR + kb * 32 + quad * 8);
#pragma unroll
    for (int nt = 0; nt < 8; ++nt) {
      bf16x8 bb = *(const bf16x8*)(Wsw + (size_t)(((nt * 4 + kb) * 64 + lane) * 8));
      acc[nt] = __builtin_amdgcn_mfma_f32_16x16x32_bf16(a, bb, acc[nt], 0, 0, 0);
    }
  }

  const float4 b0 = *(const float4*)(scsh + 2 * CC + m * 8);
  const float4 b1 = *(const float4*)(scsh + 2 * CC + m * 8 + 4);
  const float bv[8] = {b0.x, b0.y, b0.z, b0.w, b1.x, b1.y, b1.z, b1.w};

#pragma unroll
  for (int reg = 0; reg < 4; ++reg) {
    const int R = rowbase + quad * 4 + reg;
    if (R >= NN) continue;
    bf16x8 hv;
#pragma unroll
    for (int nt = 0; nt < 8; ++nt) hv[nt] = f2bf(acc[nt][reg] + bv[nt]);
    *(bf16x8*)(hout + (size_t)R * CC + m * 8) = hv;
  }
}

// ---------------------------------------------------------------------------
// K3: one block per bucket. segbase from LDS scan of bhist; per-dst histogram
// + scan -> off[]; scatter srcs into LDS csr segment; coalesced copy-out.
// ---------------------------------------------------------------------------
__global__ __launch_bounds__(256) void bucket_to_csr(
    const int2* __restrict__ ebuf, const int* __restrict__ bhist,
    int* __restrict__ off, int* __restrict__ csr) {
  __shared__ int gs[NBUK];
  __shared__ int dh[512];
  __shared__ int s[512];
  __shared__ int lcur[512];
  __shared__ int lcsr[CAP];  // 40 KB
  const int b = blockIdx.x, t = threadIdx.x;
  excl_scan256(gs, t, bhist[t]);
  const int segbase = gs[b];
  const int seglen = bhist[b];
  const int lo = b * DPB;
  const int hi = min(NN, lo + DPB);
  const int nd = hi - lo;
  const int2* eb = ebuf + segbase;

  for (int i = t; i < 512; i += 256) dh[i] = 0;
  __syncthreads();
  for (int i = t; i < seglen; i += 256) atomicAdd(&dh[eb[i].y - lo], 1);
  __syncthreads();

  for (int i = t; i < 512; i += 256) s[i] = dh[i];
  __syncthreads();
  for (int d = 1; d < 512; d <<= 1) {
    const int a0 = (t >= d) ? s[t - d] : 0;
    const int a1 = (t + 256 >= d) ? s[t + 256 - d] : 0;
    __syncthreads();
    s[t] += a0;
    s[t + 256] += a1;
    __syncthreads();
  }
  for (int i = t; i < 512; i += 256) lcur[i] = s[i] - dh[i];  // exclusive
  for (int d = t; d < nd; d += 256) off[lo + d] = segbase + (s[d] - dh[d]);
  if (b == NBUK - 1 && t == 0) off[NN] = NE;
  __syncthreads();

  if (seglen <= CAP) {
    for (int i = t; i < seglen; i += 256) {
      const int2 e = eb[i];
      const int p = atomicAdd(&lcur[e.y - lo], 1);
      lcsr[p] = e.x;
    }
    __syncthreads();
    for (int i = t; i < seglen; i += 256) csr[segbase + i] = lcsr[i];
  } else {
    for (int i = t; i < seglen; i += 256) {
      const int2 e = eb[i];
      const int p = atomicAdd(&lcur[e.y - lo], 1);
      csr[segbase + p] = e.x;
    }
  }
}

// ---------------------------------------------------------------------------
// K4: gather (r8 best, untouched): one wave per dst node; lane owns uint col
// = lane; 8-deep edge unroll for MLP on the dependent csr->h chain.
// ---------------------------------------------------------------------------
__global__ __launch_bounds__(256) void gather_bn_relu(
    const short* __restrict__ h, const int* __restrict__ off,
    const int* __restrict__ csr, const float* __restrict__ scsh,
    float* __restrict__ out) {
  const int node = (blockIdx.x * 256 + threadIdx.x) >> 6;
  const int lane = threadIdx.x & 63;
  if (node >= NN) return;
  const int s = off[node], e = off[node + 1];
  const unsigned* hb = (const unsigned*)h;

  float ax = 0.f, ay = 0.f;
  int i = s;
  for (; i + 7 < e; i += 8) {
    const int s0 = csr[i + 0], s1 = csr[i + 1], s2 = csr[i + 2], s3 = csr[i + 3];
    const int s4 = csr[i + 4], s5 = csr[i + 5], s6 = csr[i + 6], s7 = csr[i + 7];
    const unsigned p0 = hb[(size_t)s0 * 64 + lane];
    const unsigned p1 = hb[(size_t)s1 * 64 + lane];
    const unsigned p2 = hb[(size_t)s2 * 64 + lane];
    const unsigned p3 = hb[(size_t)s3 * 64 + lane];
    const unsigned p4 = hb[(size_t)s4 * 64 + lane];
    const unsigned p5 = hb[(size_t)s5 * 64 + lane];
    const unsigned p6 = hb[(size_t)s6 * 64 + lane];
    const unsigned p7 = hb[(size_t)s7 * 64 + lane];
    ax += ((bflo(p0) + bflo(p1)) + (bflo(p2) + bflo(p3))) +
          ((bflo(p4) + bflo(p5)) + (bflo(p6) + bflo(p7)));
    ay += ((bfhi(p0) + bfhi(p1)) + (bfhi(p2) + bfhi(p3))) +
          ((bfhi(p4) + bfhi(p5)) + (bfhi(p6) + bfhi(p7)));
  }
  for (; i + 3 < e; i += 4) {
    const int s0 = csr[i + 0], s1 = csr[i + 1], s2 = csr[i + 2], s3 = csr[i + 3];
    const unsigned p0 = hb[(size_t)s0 * 64 + lane];
    const unsigned p1 = hb[(size_t)s1 * 64 + lane];
    const unsigned p2 = hb[(size_t)s2 * 64 + lane];
    const unsigned p3 = hb[(size_t)s3 * 64 + lane];
    ax += (bflo(p0) + bflo(p1)) + (bflo(p2) + bflo(p3));
    ay += (bfhi(p0) + bfhi(p1)) + (bfhi(p2) + bfhi(p3));
  }
  for (; i < e; ++i) {
    const unsigned p = hb[(size_t)csr[i] * 64 + lane];
    ax += bflo(p);
    ay += bfhi(p);
  }
  const float inv = (e > s) ? 1.0f / (float)(e - s) : 0.0f;
  const float2 sc = *(const float2*)(scsh + 2 * lane);
  const float2 sh = *(const float2*)(scsh + CC + 2 * lane);
  float2 o;
  o.x = fmaxf(0.f, ax * inv * sc.x + sh.x);
  o.y = fmaxf(0.f, ay * inv * sc.y + sh.y);
  *(float2*)(out + (size_t)node * CC + lane * 2) = o;
}

// ---------------------------------------------------------------------------
// Fallback (small ws): atomic scatter + fp32 vector GEMM.
// ---------------------------------------------------------------------------
__global__ __launch_bounds__(256) void edge_scatter(
    const float* __restrict__ x, const int* __restrict__ ei,
    float* __restrict__ sums, int* __restrict__ cnt) {
  int gt = blockIdx.x * 256 + threadIdx.x;
  int e = gt >> 5;
  int sub = gt & 31;
  if (e >= NE) return;
  int src = ei[e];
  int dst = ei[NE + e];
  const float4 v = *(const float4*)(x + (size_t)src * CC + sub * 4);
  float* o = sums + (size_t)dst * CC + sub * 4;
  unsafeAtomicAdd(o + 0, v.x);
  unsafeAtomicAdd(o + 1, v.y);
  unsafeAtomicAdd(o + 2, v.z);
  unsafeAtomicAdd(o + 3, v.w);
  if (sub == 0) atomicAdd(cnt + dst, 1);
}

__global__ __launch_bounds__(256) void gemm_bn_relu_fb(
    float* buf, const float* __restrict__ W, const float* __restrict__ bias,
    const float* __restrict__ gamma, const float* __restrict__ beta,
    const float* __restrict__ rmean, const float* __restrict__ rvar,
    const int* __restrict__ cnt) {
  __shared__ float xsT[CC][65];
  const int t = threadIdx.x;
  const int n0 = blockIdx.x * 64;
  for (int j = 0; j < 8; ++j) {
    int i = t + 256 * j;
    int row = i >> 5;
    int ko = (i & 31) * 4;
    float4 v = make_float4(0.f, 0.f, 0.f, 0.f);
    if (n0 + row < NN) v = *(const float4*)(buf + (size_t)(n0 + row) * CC + ko);
    xsT[ko + 0][row] = v.x;
    xsT[ko + 1][row] = v.y;
    xsT[ko + 2][row] = v.z;
    xsT[ko + 3][row] = v.w;
  }
  __syncthreads();
  const int cg = t & 31;
  const int ng8 = (t >> 5) * 8;
  float acc[8][4];
#pragma unroll
  for (int j = 0; j < 8; ++j)
#pragma unroll
    for (int c = 0; c < 4; ++c) acc[j][c] = 0.f;
#pragma unroll 8
  for (int k = 0; k < CC; ++k) {
    const float4 wv = *(const float4*)(W + k * CC + cg * 4);
#pragma unroll
    for (int j = 0; j < 8; ++j) {
      const float xv = xsT[k][ng8 + j];
      acc[j][0] = fmaf(xv, wv.x, acc[j][0]);
      acc[j][1] = fmaf(xv, wv.y, acc[j][1]);
      acc[j][2] = fmaf(xv, wv.z, acc[j][2]);
      acc[j][3] = fmaf(xv, wv.w, acc[j][3]);
    }
  }
  const float4 bb = *(const float4*)(bias + cg * 4);
  const float4 gg = *(const float4*)(gamma + cg * 4);
  const float4 bt = *(const float4*)(beta + cg * 4);
  const float4 mu = *(const float4*)(rmean + cg * 4);
  const float4 vr = *(const float4*)(rvar + cg * 4);
  float sc[4], sh[4];
  sc[0] = gg.x * rsqrtf(vr.x + BN_EPS);
  sc[1] = gg.y * rsqrtf(vr.y + BN_EPS);
  sc[2] = gg.z * rsqrtf(vr.z + BN_EPS);
  sc[3] = gg.w * rsqrtf(vr.w + BN_EPS);
  sh[0] = bt.x - mu.x * sc[0];
  sh[1] = bt.y - mu.y * sc[1];
  sh[2] = bt.z - mu.z * sc[2];
  sh[3] = bt.w - mu.w * sc[3];
#pragma unroll
  for (int j = 0; j < 8; ++j) {
    const int n = n0 + ng8 + j;
    if (n >= NN) continue;
    const int cn = cnt[n];
    const float inv = cn > 0 ? 1.0f / (float)cn : 0.0f;
    const float bsel = cn > 0 ? 1.0f : 0.0f;
    float4 o;
    o.x = fmaxf(0.f, (acc[j][0] * inv + bsel * bb.x) * sc[0] + sh[0]);
    o.y = fmaxf(0.f, (acc[j][1] * inv + bsel * bb.y) * sc[1] + sh[1]);
    o.z = fmaxf(0.f, (acc[j][2] * inv + bsel * bb.z) * sc[2] + sh[2]);
    o.w = fmaxf(0.f, (acc[j][3] * inv + bsel * bb.w) * sc[3] + sh[3]);
    *(float4*)(buf + (size_t)n * CC + cg * 4) = o;
  }
}

extern "C" void kernel_launch(void* const* d_in, const int* in_sizes, int n_in,
                              void* d_out, int out_size, void* d_ws, size_t ws_size,
                              hipStream_t stream) {
  const float* x     = (const float*)d_in[0];
  const int*   ei    = (const int*)d_in[1];
  const float* W     = (const float*)d_in[2];
  const float* bias  = (const float*)d_in[3];
  const float* gamma = (const float*)d_in[4];
  const float* beta  = (const float*)d_in[5];
  const float* rmean = (const float*)d_in[6];
  const float* rvar  = (const float*)d_in[7];
  float* out = (float*)d_out;

  // ws layout (bytes):
  //   off[NN+1] | bhist[256] | gcurz[256] (contiguous -> one 2KB memset)
  //   | csr[NE] | scsh[384f] | Wsw[16384 bf16] | ebuf int2[NE] | h[NN*CC bf16]
  const size_t OFF_B  = 0;
  const size_t BH_B   = 400128;
  const size_t GC_B   = 401152;
  const size_t CSR_B  = 802304;
  const size_t SCSH_B = 7202304;
  const size_t WSW_B  = 7204352;
  const size_t EB_B   = 7237120;
  const size_t H1_B   = 20037120;                     // tier-1 h (after ebuf)
  const size_t NEED1  = H1_B + (size_t)NN * CC * 2;   // 45,637,120
  const size_t NEED2  = EB_B + (size_t)NN * CC * 2;   // 32,837,120 (alias)

  if (ws_size >= NEED2) {
    int*   off   = (int*)((char*)d_ws + OFF_B);
    int*   bhist = (int*)((char*)d_ws + BH_B);
    int*   gcurz = (int*)((char*)d_ws + GC_B);
    int*   csr   = (int*)((char*)d_ws + CSR_B);
    float* scsh  = (float*)((char*)d_ws + SCSH_B);
    short* Wsw   = (short*)((char*)d_ws + WSW_B);

    hipMemsetAsync(bhist, 0, 2048, stream);  // bhist + gcurz
    prep_hist<<<ABLK, 256, 0, stream>>>(W, bias, gamma, beta, rmean, rvar,
                                        ei, Wsw, scsh, bhist);
    if (ws_size >= NEED1) {
      // tier 1: fused scatter+linear (ebuf and h distinct)
      int2*  ebuf = (int2*)((char*)d_ws + EB_B);
      short* h    = (short*)((char*)d_ws + H1_B);
      scatter_linear<<<ABLK + LBLK, 256, 0, stream>>>(
          ei, bhist, gcurz, ebuf, x, Wsw, scsh, h, ABLK);
      bucket_to_csr<<<NBUK, 256, 0, stream>>>(ebuf, bhist, off, csr);
      gather_bn_relu<<<(NN * 64 + 255) / 256, 256, 0, stream>>>(h, off, csr,
                                                                scsh, out);
    } else {
      // tier 2: un-fused, ebuf aliases h (r8-proven ordering)
      int2*  ebuf = (int2*)((char*)d_ws + EB_B);
      short* h    = (short*)((char*)d_ws + EB_B);
      scatter_linear<<<ABLK, 256, 0, stream>>>(
          ei, bhist, gcurz, ebuf, x, Wsw, scsh, h, ABLK);  // scatter only
      bucket_to_csr<<<NBUK, 256, 0, stream>>>(ebuf, bhist, off, csr);
      scatter_linear<<<LBLK, 256, 0, stream>>>(
          ei, bhist, gcurz, ebuf, x, Wsw, scsh, h, 0);     // linear only
      gather_bn_relu<<<(NN * 64 + 255) / 256, 256, 0, stream>>>(h, off, csr,
                                                                scsh, out);
    }
  } else {
    int* cnt = (int*)d_ws;
    hipMemsetAsync(out, 0, (size_t)NN * CC * sizeof(float), stream);
    hipMemsetAsync(cnt, 0, (size_t)NN * sizeof(int), stream);
    edge_scatter<<<(NE * 32) / 256, 256, 0, stream>>>(x, ei, out, cnt);
    gemm_bn_relu_fb<<<(NN + 63) / 64, 256, 0, stream>>>(
        out, W, bias, gamma, beta, rmean, rvar, cnt);
  }
}